// Round 1
// baseline (702.256 us; speedup 1.0000x reference)
//
#include <hip/hip_runtime.h>
#include <math.h>

// Problem constants: B=16, C_in=256, H=W=32 -> N=1024, qkv_out=1536,
// HEAD=8, dh=dv=64, V_DIM=512, OUT_CH=256.
static constexpr int Bsz = 16;
static constexpr int Np  = 1024;
static constexpr int Cin = 256;

// ---------------------------------------------------------------------------
// Kernel 1: QKV 1x1-conv GEMM + head scatter.
// qkv[b,o,n] = sum_c x[b,c,n] * w[o,c] + bias[o]; o in [0,1536).
// Per batch: C[o,n] tile 128(o) x 128(n), K-chunk 16, micro 8x8.
// thread: tx(0..15) -> o, ty(0..15) -> n. LDS operands stored k-major so
// compute reads are lanes-on-columns (2-way bank aliasing = free).
// Epilogue scatters to q/k/v buffers in [b*8+head][n][64] layout, float4
// along dim (coalesced: 16 lanes x 16B = 256B rows).
// ---------------------------------------------------------------------------
__global__ __launch_bounds__(256)
void qkv_gemm(const float* __restrict__ x, const float* __restrict__ w,
              const float* __restrict__ bias,
              float* __restrict__ qb, float* __restrict__ kb, float* __restrict__ vb)
{
    __shared__ float Wt[16][132];   // [k][o]  (transposed fill)
    __shared__ float Xt[16][132];   // [k][n]  (direct fill)
    const int t = threadIdx.x, tx = t & 15, ty = t >> 4;
    const int n0 = blockIdx.x * 128;
    const int o0 = blockIdx.y * 128;
    const int b  = blockIdx.z;

    float acc[8][8];
#pragma unroll
    for (int i = 0; i < 8; ++i)
#pragma unroll
        for (int j = 0; j < 8; ++j) acc[i][j] = 0.f;

    for (int k0 = 0; k0 < Cin; k0 += 16) {
        __syncthreads();
        {   // Wt fill: 128 o x 16 k, transposed scatter (amortized 1:16 vs reads)
            const int kc4 = (t & 3) * 4;
            int o_l = t >> 2;
#pragma unroll
            for (int g = 0; g < 2; ++g, o_l += 64) {
                const float4 v = *(const float4*)&w[(o0 + o_l) * Cin + k0 + kc4];
                Wt[kc4 + 0][o_l] = v.x; Wt[kc4 + 1][o_l] = v.y;
                Wt[kc4 + 2][o_l] = v.z; Wt[kc4 + 3][o_l] = v.w;
            }
        }
        {   // Xt fill: 16 k x 128 n, direct float4 (n contiguous in x)
            const int kc = t >> 4, n8 = (t & 15) * 8;
            const float* s = &x[(b * Cin + k0 + kc) * Np + n0 + n8];
            *(float4*)&Xt[kc][n8]     = *(const float4*)(s);
            *(float4*)&Xt[kc][n8 + 4] = *(const float4*)(s + 4);
        }
        __syncthreads();
#pragma unroll
        for (int kc = 0; kc < 16; ++kc) {
            float a[8], bv[8];
            *(float4*)&a[0]  = *(const float4*)&Wt[kc][4 * tx];
            *(float4*)&a[4]  = *(const float4*)&Wt[kc][64 + 4 * tx];
            *(float4*)&bv[0] = *(const float4*)&Xt[kc][4 * ty];
            *(float4*)&bv[4] = *(const float4*)&Xt[kc][64 + 4 * ty];
#pragma unroll
            for (int i = 0; i < 8; ++i)
#pragma unroll
                for (int j = 0; j < 8; ++j) acc[i][j] += bv[i] * a[j];
        }
    }

    // o-tile (128-wide, o0 multiple of 128) lies entirely in one of q/k/v and
    // spans exactly two heads.
    float* dst; int obase;
    if (o0 < 512)       { dst = qb; obase = o0; }
    else if (o0 < 1024) { dst = kb; obase = o0 - 512; }
    else                { dst = vb; obase = o0 - 1024; }
    const int head0 = obase >> 6;

#pragma unroll
    for (int h = 0; h < 2; ++h) {
        float bs[4];
#pragma unroll
        for (int e = 0; e < 4; ++e) bs[e] = bias[o0 + 64 * h + 4 * tx + e];
        const int bh = b * 8 + head0 + h;
#pragma unroll
        for (int i = 0; i < 8; ++i) {
            const int n = n0 + 64 * (i >> 2) + 4 * ty + (i & 3);
            float4 v;
            v.x = acc[i][4 * h + 0] + bs[0];
            v.y = acc[i][4 * h + 1] + bs[1];
            v.z = acc[i][4 * h + 2] + bs[2];
            v.w = acc[i][4 * h + 3] + bs[3];
            *(float4*)&dst[((bh * Np + n) << 6) + 4 * tx] = v;
        }
    }
}

// ---------------------------------------------------------------------------
// Kernel 2: causal flash attention, fp32. One block per (bh, q-tile of 64).
// Q,K stored transposed [d][row] in LDS so score-phase reads are b128s with
// lanes on columns. P (exp scores) aliases the K tile (KP) -> 53 KB LDS,
// 3 blocks/CU. Online softmax state (m,l,alpha) in LDS; shuffle reductions
// over the 16 tx lanes (lane bits 0..3). Causal: only kt <= qt tiles.
// ---------------------------------------------------------------------------
__global__ __launch_bounds__(256)
void attn(const float* __restrict__ qb, const float* __restrict__ kb,
          const float* __restrict__ vb, float* __restrict__ ob)
{
    __shared__ float Qt[64][68];   // [d][q]
    __shared__ float KP[64][68];   // Kt [d][k] during scores; P [q][k] during PV
    __shared__ float Vs[64][68];   // [k][d]
    __shared__ float m_s[64], l_s[64], al_s[64];

    const int t = threadIdx.x, tx = t & 15, ty = t >> 4;
    const int qt = blockIdx.x & 15;
    const int bh = blockIdx.x >> 4;
    const int q0 = qt * 64;

    {   // Q tile, transposed fill (once per block, reused over k-tiles)
        const int r = t >> 2;
#pragma unroll
        for (int dd = 0; dd < 4; ++dd) {
            const int d4 = (t & 3) * 4 + dd * 16;
            const float4 v = *(const float4*)&qb[((bh * Np + q0 + r) << 6) + d4];
            Qt[d4 + 0][r] = v.x; Qt[d4 + 1][r] = v.y;
            Qt[d4 + 2][r] = v.z; Qt[d4 + 3][r] = v.w;
        }
    }
    if (t < 64) { m_s[t] = -INFINITY; l_s[t] = 0.f; }

    float accO[4][4];
#pragma unroll
    for (int i = 0; i < 4; ++i)
#pragma unroll
        for (int j = 0; j < 4; ++j) accO[i][j] = 0.f;

    for (int kt = 0; kt <= qt; ++kt) {
        __syncthreads();   // prev PV done (and Qt fill visible on first iter)
        {   // K (transposed) + V (direct) tile fills
            const int r = t >> 2;
            const int base = (bh * Np + kt * 64 + r) << 6;
#pragma unroll
            for (int dd = 0; dd < 4; ++dd) {
                const int d4 = (t & 3) * 4 + dd * 16;
                const float4 kv = *(const float4*)&kb[base + d4];
                KP[d4 + 0][r] = kv.x; KP[d4 + 1][r] = kv.y;
                KP[d4 + 2][r] = kv.z; KP[d4 + 3][r] = kv.w;
                *(float4*)&Vs[r][d4] = *(const float4*)&vb[base + d4];
            }
        }
        __syncthreads();

        // S = Q K^T
        float sc[4][4];
#pragma unroll
        for (int i = 0; i < 4; ++i)
#pragma unroll
            for (int j = 0; j < 4; ++j) sc[i][j] = 0.f;
#pragma unroll 8
        for (int d = 0; d < 64; ++d) {
            float qv[4], kv[4];
            *(float4*)&qv[0] = *(const float4*)&Qt[d][4 * ty];
            *(float4*)&kv[0] = *(const float4*)&KP[d][4 * tx];
#pragma unroll
            for (int i = 0; i < 4; ++i)
#pragma unroll
                for (int j = 0; j < 4; ++j) sc[i][j] += qv[i] * kv[j];
        }

        // scale, causal mask (diag tile only), row max
        const bool diag = (kt == qt);
        float mx[4];
#pragma unroll
        for (int i = 0; i < 4; ++i) {
            float m = -INFINITY;
#pragma unroll
            for (int j = 0; j < 4; ++j) {
                float s = sc[i][j] * 0.125f;
                if (diag && (4 * tx + j > 4 * ty + i)) s = -INFINITY;
                sc[i][j] = s;
                m = fmaxf(m, s);
            }
            mx[i] = m;
        }
#pragma unroll
        for (int off = 8; off >= 1; off >>= 1)
#pragma unroll
            for (int i = 0; i < 4; ++i) mx[i] = fmaxf(mx[i], __shfl_xor(mx[i], off));

        if (tx == 0) {
#pragma unroll
            for (int i = 0; i < 4; ++i) {
                const int r = 4 * ty + i;
                const float mo = m_s[r];
                const float mn = fmaxf(mo, mx[i]);
                al_s[r] = __expf(mo - mn);   // expf(-inf)=0 on first tile
                m_s[r]  = mn;
            }
        }
        __syncthreads();   // m_s/al_s visible; scores-phase Kt reads done

        // P = exp(S - m), row sums; P overwrites the K tile (safe post-sync)
        float rs[4], al[4];
#pragma unroll
        for (int i = 0; i < 4; ++i) {
            const int r = 4 * ty + i;
            const float mn = m_s[r];
            float s = 0.f;
#pragma unroll
            for (int j = 0; j < 4; ++j) {
                const float p = __expf(sc[i][j] - mn);
                KP[r][4 * tx + j] = p;
                s += p;
            }
            rs[i] = s;
            al[i] = al_s[r];
        }
#pragma unroll
        for (int off = 8; off >= 1; off >>= 1)
#pragma unroll
            for (int i = 0; i < 4; ++i) rs[i] += __shfl_xor(rs[i], off);

#pragma unroll
        for (int i = 0; i < 4; ++i)
#pragma unroll
            for (int j = 0; j < 4; ++j) accO[i][j] *= al[i];

        if (tx == 0) {
#pragma unroll
            for (int i = 0; i < 4; ++i) {
                const int r = 4 * ty + i;
                l_s[r] = l_s[r] * al[i] + rs[i];
            }
        }
        __syncthreads();   // P visible

        // O += P V
#pragma unroll 8
        for (int kk = 0; kk < 64; ++kk) {
            float vv[4];
            *(float4*)&vv[0] = *(const float4*)&Vs[kk][4 * tx];
#pragma unroll
            for (int i = 0; i < 4; ++i) {
                const float p = KP[4 * ty + i][kk];   // broadcast per ty-group
#pragma unroll
                for (int j = 0; j < 4; ++j) accO[i][j] += p * vv[j];
            }
        }
    }
    __syncthreads();
#pragma unroll
    for (int i = 0; i < 4; ++i) {
        const int r = 4 * ty + i;
        const float inv = 1.0f / l_s[r];
        float4 v;
        v.x = accO[i][0] * inv; v.y = accO[i][1] * inv;
        v.z = accO[i][2] * inv; v.w = accO[i][3] * inv;
        *(float4*)&ob[((bh * Np + q0 + r) << 6) + 4 * tx] = v;
    }
}

// ---------------------------------------------------------------------------
// Kernel 3: projection GEMM. out[b,o,n] = sum_v attn[b,v,n]*pw[o,v] + pb[o].
// attn channel v = head*64+dc lives at ob[(b*8+head)*1024+n][dc].
// Tile 64(o) x 128(n), K=512 in chunks of 16 (each chunk within one head).
// thread: tx -> n, ty -> o (n-contiguous float4 output writes).
// ---------------------------------------------------------------------------
__global__ __launch_bounds__(256)
void proj_gemm(const float* __restrict__ ob, const float* __restrict__ w,
               const float* __restrict__ bias, float* __restrict__ out)
{
    __shared__ float Wt[16][68];    // [k][o]
    __shared__ float Xt[16][132];   // [k][n]
    const int t = threadIdx.x, tx = t & 15, ty = t >> 4;
    const int n0 = blockIdx.x * 128;
    const int o0 = blockIdx.y * 64;
    const int b  = blockIdx.z;

    float acc[4][8];
#pragma unroll
    for (int i = 0; i < 4; ++i)
#pragma unroll
        for (int j = 0; j < 8; ++j) acc[i][j] = 0.f;

    for (int k0 = 0; k0 < 512; k0 += 16) {
        __syncthreads();
        {   // Wt fill: 64 o x 16 k
            const int o_l = t >> 2, kc4 = (t & 3) * 4;
            const float4 v = *(const float4*)&w[(o0 + o_l) * 512 + k0 + kc4];
            Wt[kc4 + 0][o_l] = v.x; Wt[kc4 + 1][o_l] = v.y;
            Wt[kc4 + 2][o_l] = v.z; Wt[kc4 + 3][o_l] = v.w;
        }
        {   // Xt fill: gather 16 v x 128 n from head-interleaved attn-out
            const int head = k0 >> 6, dc0 = k0 & 63;
            const int bh = b * 8 + head;
            const int dc4 = (t & 3) * 4;
            int n_l = t >> 2;
#pragma unroll
            for (int g = 0; g < 2; ++g, n_l += 64) {
                const float4 v = *(const float4*)&ob[((bh * Np + n0 + n_l) << 6) + dc0 + dc4];
                Xt[dc4 + 0][n_l] = v.x; Xt[dc4 + 1][n_l] = v.y;
                Xt[dc4 + 2][n_l] = v.z; Xt[dc4 + 3][n_l] = v.w;
            }
        }
        __syncthreads();
#pragma unroll
        for (int kc = 0; kc < 16; ++kc) {
            float a[4], bv[8];
            *(float4*)&a[0]  = *(const float4*)&Wt[kc][4 * ty];
            *(float4*)&bv[0] = *(const float4*)&Xt[kc][4 * tx];
            *(float4*)&bv[4] = *(const float4*)&Xt[kc][64 + 4 * tx];
#pragma unroll
            for (int i = 0; i < 4; ++i)
#pragma unroll
                for (int j = 0; j < 8; ++j) acc[i][j] += a[i] * bv[j];
        }
    }
#pragma unroll
    for (int i = 0; i < 4; ++i) {
        const int o = o0 + 4 * ty + i;
        const float pb = bias[o];
        float* dstrow = &out[(b * 256 + o) * Np + n0];
#pragma unroll
        for (int h = 0; h < 2; ++h) {
            float4 v;
            v.x = acc[i][4 * h + 0] + pb; v.y = acc[i][4 * h + 1] + pb;
            v.z = acc[i][4 * h + 2] + pb; v.w = acc[i][4 * h + 3] + pb;
            *(float4*)&dstrow[64 * h + 4 * tx] = v;
        }
    }
}

// ---------------------------------------------------------------------------
extern "C" void kernel_launch(void* const* d_in, const int* in_sizes, int n_in,
                              void* d_out, int out_size, void* d_ws, size_t ws_size,
                              hipStream_t stream)
{
    const float* x   = (const float*)d_in[0];   // [16,256,1024]
    const float* qw  = (const float*)d_in[1];   // [1536,256]
    const float* qbb = (const float*)d_in[2];   // [1536]
    const float* pw  = (const float*)d_in[3];   // [256,512]
    const float* pb  = (const float*)d_in[4];   // [256]
    float* out = (float*)d_out;                 // [16,256,1024]

    // workspace: q/k/v/attn-out, each [128 bh][1024 n][64 d] = 33.5 MB
    const size_t per = (size_t)Bsz * 8 * Np * 64;
    float* qbuf = (float*)d_ws;
    float* kbuf = qbuf + per;
    float* vbuf = kbuf + per;
    float* obuf = vbuf + per;

    qkv_gemm<<<dim3(8, 12, Bsz), 256, 0, stream>>>(x, qw, qbb, qbuf, kbuf, vbuf);
    attn<<<dim3(128 * 16), 256, 0, stream>>>(qbuf, kbuf, vbuf, obuf);
    proj_gemm<<<dim3(8, 4, Bsz), 256, 0, stream>>>(obuf, pw, pb, out);
}

// Round 2
// 332.278 us; speedup vs baseline: 2.1135x; 2.1135x over previous
//
#include <hip/hip_runtime.h>
#include <math.h>

// Problem constants: B=16, C_in=256, H=W=32 -> N=1024, qkv_out=1536,
// HEAD=8, dh=dv=64, V_DIM=512, OUT_CH=256.
static constexpr int Bsz = 16;
static constexpr int Np  = 1024;
static constexpr int Cin = 256;

typedef __attribute__((ext_vector_type(8))) short short8;  // 8 bf16 = 4 VGPR
typedef __attribute__((ext_vector_type(4))) float f4;      // mfma acc

// fp32 -> bf16 round-to-nearest-even
__device__ __forceinline__ unsigned short f2b(float f) {
    union { float fp; unsigned int u; } v; v.fp = f;
    unsigned int r = v.u + 0x7fffu + ((v.u >> 16) & 1u);
    return (unsigned short)(r >> 16);
}

// ---------------------------------------------------------------------------
// Kernel 1: QKV 1x1-conv GEMM (fp32 compute) + head scatter, bf16 output.
// q channels pre-scaled by dh^-0.5 = 0.125 (exact in bf16: pow2 exponent).
// ---------------------------------------------------------------------------
__global__ __launch_bounds__(256)
void qkv_gemm(const float* __restrict__ x, const float* __restrict__ w,
              const float* __restrict__ bias,
              ushort* __restrict__ qb, ushort* __restrict__ kb, ushort* __restrict__ vb)
{
    __shared__ float Wt[16][132];   // [k][o]  (transposed fill)
    __shared__ float Xt[16][132];   // [k][n]  (direct fill)
    const int t = threadIdx.x, tx = t & 15, ty = t >> 4;
    const int n0 = blockIdx.x * 128;
    const int o0 = blockIdx.y * 128;
    const int b  = blockIdx.z;

    float acc[8][8];
#pragma unroll
    for (int i = 0; i < 8; ++i)
#pragma unroll
        for (int j = 0; j < 8; ++j) acc[i][j] = 0.f;

    for (int k0 = 0; k0 < Cin; k0 += 16) {
        __syncthreads();
        {   // Wt fill: 128 o x 16 k, transposed scatter
            const int kc4 = (t & 3) * 4;
            int o_l = t >> 2;
#pragma unroll
            for (int g = 0; g < 2; ++g, o_l += 64) {
                const float4 v = *(const float4*)&w[(o0 + o_l) * Cin + k0 + kc4];
                Wt[kc4 + 0][o_l] = v.x; Wt[kc4 + 1][o_l] = v.y;
                Wt[kc4 + 2][o_l] = v.z; Wt[kc4 + 3][o_l] = v.w;
            }
        }
        {   // Xt fill: 16 k x 128 n, direct float4
            const int kc = t >> 4, n8 = (t & 15) * 8;
            const float* s = &x[(b * Cin + k0 + kc) * Np + n0 + n8];
            *(float4*)&Xt[kc][n8]     = *(const float4*)(s);
            *(float4*)&Xt[kc][n8 + 4] = *(const float4*)(s + 4);
        }
        __syncthreads();
#pragma unroll
        for (int kc = 0; kc < 16; ++kc) {
            float a[8], bv[8];
            *(float4*)&a[0]  = *(const float4*)&Wt[kc][4 * tx];
            *(float4*)&a[4]  = *(const float4*)&Wt[kc][64 + 4 * tx];
            *(float4*)&bv[0] = *(const float4*)&Xt[kc][4 * ty];
            *(float4*)&bv[4] = *(const float4*)&Xt[kc][64 + 4 * ty];
#pragma unroll
            for (int i = 0; i < 8; ++i)
#pragma unroll
                for (int j = 0; j < 8; ++j) acc[i][j] += bv[i] * a[j];
        }
    }

    ushort* dst; int obase; float sc;
    if (o0 < 512)       { dst = qb; obase = o0;        sc = 0.125f; }
    else if (o0 < 1024) { dst = kb; obase = o0 - 512;  sc = 1.0f; }
    else                { dst = vb; obase = o0 - 1024; sc = 1.0f; }
    const int head0 = obase >> 6;

#pragma unroll
    for (int h = 0; h < 2; ++h) {
        float bs[4];
#pragma unroll
        for (int e = 0; e < 4; ++e) bs[e] = bias[o0 + 64 * h + 4 * tx + e];
        const int bh = b * 8 + head0 + h;
#pragma unroll
        for (int i = 0; i < 8; ++i) {
            const int n = n0 + 64 * (i >> 2) + 4 * ty + (i & 3);
            ushort4 u;
            u.x = f2b((acc[i][4 * h + 0] + bs[0]) * sc);
            u.y = f2b((acc[i][4 * h + 1] + bs[1]) * sc);
            u.z = f2b((acc[i][4 * h + 2] + bs[2]) * sc);
            u.w = f2b((acc[i][4 * h + 3] + bs[3]) * sc);
            *(ushort4*)&dst[((bh * Np + n) << 6) + 4 * tx] = u;
        }
    }
}

// ---------------------------------------------------------------------------
// Kernel 2: causal flash attention, bf16 MFMA (16x16x32), fp32 softmax.
// One block per (bh, 64-row q-tile); 4 waves, wave w owns q rows [w*16,w*16+16).
// LDS stride 72 ushorts (144B): 16B-aligned b128 frag reads, 2-way bank
// aliasing only (free). Softmax state in registers (C/D rows = quad*4+reg,
// reduction over lane bits 0..3). P round-trips LDS (C/D -> A layout), but
// each wave's P strip is private -> no barrier between P write and read.
// ---------------------------------------------------------------------------
__global__ __launch_bounds__(256, 4)
void attn(const ushort* __restrict__ qb, const ushort* __restrict__ kb,
          const ushort* __restrict__ vb, float* __restrict__ ob)
{
    __shared__ ushort Qs[64 * 72];   // [q][d]
    __shared__ ushort Ks[64 * 72];   // [k][d]
    __shared__ ushort Vt[64 * 72];   // [d][k] (transposed)
    __shared__ ushort Ps[64 * 72];   // [q][k]

    const int t    = threadIdx.x;
    const int w    = t >> 6;        // wave id
    const int lane = t & 63;
    const int quad = lane >> 4;
    const int ln   = lane & 15;
    const int bh   = blockIdx.x & 127;
    const int qt   = 15 - (blockIdx.x >> 7);   // heavy (large qt) blocks first
    const int q0   = qt * 64;

    {   // stage Q tile (q pre-scaled by 0.125 in qkv epilogue)
        const int r = t & 63, seg = t >> 6;
        const ushort* src = &qb[((bh * Np + q0 + r) << 6) + seg * 16];
        *(uint4*)&Qs[r * 72 + seg * 16]     = *(const uint4*)src;
        *(uint4*)&Qs[r * 72 + seg * 16 + 8] = *(const uint4*)(src + 8);
    }
    __syncthreads();

    // Q A-frags for this wave's 16-row strip (reused over all k-tiles)
    short8 qa0 = *(const short8*)&Qs[(w * 16 + ln) * 72 + quad * 8];
    short8 qa1 = *(const short8*)&Qs[(w * 16 + ln) * 72 + 32 + quad * 8];

    f4 o[4];
#pragma unroll
    for (int nt = 0; nt < 4; ++nt) o[nt] = (f4){0.f, 0.f, 0.f, 0.f};
    float mrun[4], lrun[4];
#pragma unroll
    for (int rg = 0; rg < 4; ++rg) { mrun[rg] = -INFINITY; lrun[rg] = 0.f; }

    for (int kt = 0; kt <= qt; ++kt) {
        __syncthreads();   // prior-iter Ks/Vt reads done before overwrite
        {   // stage K [k][d] and V transposed [d][k]
            const int r = t & 63, seg = t >> 6;
            const int gbase = ((bh * Np + kt * 64 + r) << 6) + seg * 16;
            *(uint4*)&Ks[r * 72 + seg * 16]     = *(const uint4*)&kb[gbase];
            *(uint4*)&Ks[r * 72 + seg * 16 + 8] = *(const uint4*)&kb[gbase + 8];
            ushort tmp[16];
            *(uint4*)&tmp[0] = *(const uint4*)&vb[gbase];
            *(uint4*)&tmp[8] = *(const uint4*)&vb[gbase + 8];
#pragma unroll
            for (int e = 0; e < 16; ++e) Vt[(seg * 16 + e) * 72 + r] = tmp[e];
        }
        __syncthreads();

        // ---- S = Q K^T : 4 n-tiles x 2 k-steps
        f4 s[4];
#pragma unroll
        for (int nt = 0; nt < 4; ++nt) s[nt] = (f4){0.f, 0.f, 0.f, 0.f};
#pragma unroll
        for (int nt = 0; nt < 4; ++nt) {
            short8 b0 = *(const short8*)&Ks[(nt * 16 + ln) * 72 + quad * 8];
            short8 b1 = *(const short8*)&Ks[(nt * 16 + ln) * 72 + 32 + quad * 8];
            s[nt] = __builtin_amdgcn_mfma_f32_16x16x32_bf16(qa0, b0, s[nt], 0, 0, 0);
            s[nt] = __builtin_amdgcn_mfma_f32_16x16x32_bf16(qa1, b1, s[nt], 0, 0, 0);
        }

        // ---- causal mask (diag tile only): col nt*16+ln vs row w*16+quad*4+rg
        if (kt == qt) {
            const int qr = w * 16 + quad * 4;
#pragma unroll
            for (int nt = 0; nt < 4; ++nt) {
                const int kc = nt * 16 + ln;
#pragma unroll
                for (int rg = 0; rg < 4; ++rg)
                    if (kc > qr + rg) s[nt][rg] = -INFINITY;
            }
        }

        // ---- online softmax (row = quad*4+rg, cols spread over nt x 16 lanes)
        float mx[4];
#pragma unroll
        for (int rg = 0; rg < 4; ++rg)
            mx[rg] = fmaxf(fmaxf(s[0][rg], s[1][rg]), fmaxf(s[2][rg], s[3][rg]));
#pragma unroll
        for (int off = 1; off < 16; off <<= 1)
#pragma unroll
            for (int rg = 0; rg < 4; ++rg)
                mx[rg] = fmaxf(mx[rg], __shfl_xor(mx[rg], off));

        float al[4];
#pragma unroll
        for (int rg = 0; rg < 4; ++rg) {
            const float mn = fmaxf(mrun[rg], mx[rg]);
            al[rg]   = __expf(mrun[rg] - mn);   // first tile: expf(-inf)=0
            mrun[rg] = mn;
        }

        float rs[4] = {0.f, 0.f, 0.f, 0.f};
        const int prow = (w * 16 + quad * 4) * 72 + ln;
#pragma unroll
        for (int nt = 0; nt < 4; ++nt)
#pragma unroll
            for (int rg = 0; rg < 4; ++rg) {
                const float p = __expf(s[nt][rg] - mrun[rg]);
                Ps[prow + rg * 72 + nt * 16] = f2b(p);
                rs[rg] += p;
            }
#pragma unroll
        for (int off = 1; off < 16; off <<= 1)
#pragma unroll
            for (int rg = 0; rg < 4; ++rg) rs[rg] += __shfl_xor(rs[rg], off);

#pragma unroll
        for (int rg = 0; rg < 4; ++rg) lrun[rg] = lrun[rg] * al[rg] + rs[rg];
#pragma unroll
        for (int nt = 0; nt < 4; ++nt)
#pragma unroll
            for (int rg = 0; rg < 4; ++rg) o[nt][rg] *= al[rg];

        // ---- O += P V  (P strip is wave-private; DS ops in-order within wave)
#pragma unroll
        for (int ks = 0; ks < 2; ++ks) {
            short8 pa = *(const short8*)&Ps[(w * 16 + ln) * 72 + ks * 32 + quad * 8];
#pragma unroll
            for (int nt = 0; nt < 4; ++nt) {
                short8 vf = *(const short8*)&Vt[(nt * 16 + ln) * 72 + ks * 32 + quad * 8];
                o[nt] = __builtin_amdgcn_mfma_f32_16x16x32_bf16(pa, vf, o[nt], 0, 0, 0);
            }
        }
    }

    // ---- epilogue: O / l -> fp32 obuf [bh][q][64]
    float inv[4];
#pragma unroll
    for (int rg = 0; rg < 4; ++rg) inv[rg] = 1.0f / lrun[rg];
#pragma unroll
    for (int rg = 0; rg < 4; ++rg) {
        const int r = q0 + w * 16 + quad * 4 + rg;
#pragma unroll
        for (int nt = 0; nt < 4; ++nt)
            ob[((bh * Np + r) << 6) + nt * 16 + ln] = o[nt][rg] * inv[rg];
    }
}

// ---------------------------------------------------------------------------
// Kernel 3: projection GEMM (fp32). out[b,o,n] = sum_v attn[b,v,n]*pw[o,v]+pb.
// ---------------------------------------------------------------------------
__global__ __launch_bounds__(256)
void proj_gemm(const float* __restrict__ ob, const float* __restrict__ w,
               const float* __restrict__ bias, float* __restrict__ out)
{
    __shared__ float Wt[16][68];    // [k][o]
    __shared__ float Xt[16][132];   // [k][n]
    const int t = threadIdx.x, tx = t & 15, ty = t >> 4;
    const int n0 = blockIdx.x * 128;
    const int o0 = blockIdx.y * 64;
    const int b  = blockIdx.z;

    float acc[4][8];
#pragma unroll
    for (int i = 0; i < 4; ++i)
#pragma unroll
        for (int j = 0; j < 8; ++j) acc[i][j] = 0.f;

    for (int k0 = 0; k0 < 512; k0 += 16) {
        __syncthreads();
        {   // Wt fill: 64 o x 16 k
            const int o_l = t >> 2, kc4 = (t & 3) * 4;
            const float4 v = *(const float4*)&w[(o0 + o_l) * 512 + k0 + kc4];
            Wt[kc4 + 0][o_l] = v.x; Wt[kc4 + 1][o_l] = v.y;
            Wt[kc4 + 2][o_l] = v.z; Wt[kc4 + 3][o_l] = v.w;
        }
        {   // Xt fill: gather 16 v x 128 n from head-interleaved attn-out
            const int head = k0 >> 6, dc0 = k0 & 63;
            const int bh = b * 8 + head;
            const int dc4 = (t & 3) * 4;
            int n_l = t >> 2;
#pragma unroll
            for (int g = 0; g < 2; ++g, n_l += 64) {
                const float4 v = *(const float4*)&ob[((bh * Np + n0 + n_l) << 6) + dc0 + dc4];
                Xt[dc4 + 0][n_l] = v.x; Xt[dc4 + 1][n_l] = v.y;
                Xt[dc4 + 2][n_l] = v.z; Xt[dc4 + 3][n_l] = v.w;
            }
        }
        __syncthreads();
#pragma unroll
        for (int kc = 0; kc < 16; ++kc) {
            float a[4], bv[8];
            *(float4*)&a[0]  = *(const float4*)&Wt[kc][4 * ty];
            *(float4*)&bv[0] = *(const float4*)&Xt[kc][4 * tx];
            *(float4*)&bv[4] = *(const float4*)&Xt[kc][64 + 4 * tx];
#pragma unroll
            for (int i = 0; i < 4; ++i)
#pragma unroll
                for (int j = 0; j < 8; ++j) acc[i][j] += a[i] * bv[j];
        }
    }
#pragma unroll
    for (int i = 0; i < 4; ++i) {
        const int o = o0 + 4 * ty + i;
        const float pb = bias[o];
        float* dstrow = &out[(b * 256 + o) * Np + n0];
#pragma unroll
        for (int h = 0; h < 2; ++h) {
            float4 v;
            v.x = acc[i][4 * h + 0] + pb; v.y = acc[i][4 * h + 1] + pb;
            v.z = acc[i][4 * h + 2] + pb; v.w = acc[i][4 * h + 3] + pb;
            *(float4*)&dstrow[64 * h + 4 * tx] = v;
        }
    }
}

// ---------------------------------------------------------------------------
extern "C" void kernel_launch(void* const* d_in, const int* in_sizes, int n_in,
                              void* d_out, int out_size, void* d_ws, size_t ws_size,
                              hipStream_t stream)
{
    const float* x   = (const float*)d_in[0];   // [16,256,1024]
    const float* qw  = (const float*)d_in[1];   // [1536,256]
    const float* qbb = (const float*)d_in[2];   // [1536]
    const float* pw  = (const float*)d_in[3];   // [256,512]
    const float* pb  = (const float*)d_in[4];   // [256]
    float* out = (float*)d_out;                 // [16,256,1024]

    // workspace: q/k/v bf16 [128 bh][1024 n][64 d] = 16.8 MB each,
    // attn-out fp32 = 33.5 MB. total ~84 MB.
    const size_t per = (size_t)Bsz * 8 * Np * 64;
    ushort* qbuf = (ushort*)d_ws;
    ushort* kbuf = qbuf + per;
    ushort* vbuf = kbuf + per;
    float*  obuf = (float*)(vbuf + per);

    qkv_gemm<<<dim3(8, 12, Bsz), 256, 0, stream>>>(x, qw, qbb, qbuf, kbuf, vbuf);
    attn<<<dim3(128 * 16), 256, 0, stream>>>(qbuf, kbuf, vbuf, obuf);
    proj_gemm<<<dim3(8, 4, Bsz), 256, 0, stream>>>(obuf, pw, pb, out);
}

// Round 4
// 196.053 us; speedup vs baseline: 3.5820x; 1.6948x over previous
//
#include <hip/hip_runtime.h>
#include <math.h>

// Problem constants: B=16, C_in=256, H=W=32 -> N=1024, qkv_out=1536,
// HEAD=8, dh=dv=64, V_DIM=512, OUT_CH=256.
static constexpr int Bsz = 16;
static constexpr int Np  = 1024;
static constexpr int Cin = 256;

typedef __attribute__((ext_vector_type(8))) short short8;  // 8 bf16 = 4 VGPR
typedef __attribute__((ext_vector_type(4))) float f4;      // mfma acc

// fp32 -> bf16 round-to-nearest-even
__device__ __forceinline__ unsigned short f2b(float f) {
    union { float fp; unsigned int u; } v; v.fp = f;
    unsigned int r = v.u + 0x7fffu + ((v.u >> 16) & 1u);
    return (unsigned short)(r >> 16);
}

// ---------------------------------------------------------------------------
// Kernel 0a: cast+transpose x [b][c][n] fp32 -> xb [b][n][c] bf16.
// 64x64 tiles through LDS; coalesced float4 reads, 16B bf16 writes.
// ---------------------------------------------------------------------------
__global__ __launch_bounds__(256)
void cast_x(const float* __restrict__ x, ushort* __restrict__ xb)
{
    __shared__ ushort T[64][72];   // [n][c], stride 144B (9x16B)
    const int t = threadIdx.x;
    const int n0 = blockIdx.x * 64, c0 = blockIdx.y * 64, b = blockIdx.z;

    {   // read 64c x 64n, convert, transposed scatter into LDS
        const int c_l = t >> 2, ns = (t & 3) * 16;
        const float* src = &x[((b * Cin + c0 + c_l) << 10) + n0 + ns];
#pragma unroll
        for (int i = 0; i < 4; ++i) {
            const float4 v = *(const float4*)(src + 4 * i);
            T[ns + 4 * i + 0][c_l] = f2b(v.x);
            T[ns + 4 * i + 1][c_l] = f2b(v.y);
            T[ns + 4 * i + 2][c_l] = f2b(v.z);
            T[ns + 4 * i + 3][c_l] = f2b(v.w);
        }
    }
    __syncthreads();
    {   // write rows of c (contiguous) to xb
        const int n_l = t >> 2, cs = (t & 3) * 16;
        ushort* dst = &xb[((b << 10) + n0 + n_l) * Cin + c0 + cs];
        *(uint4*)dst       = *(const uint4*)&T[n_l][cs];
        *(uint4*)(dst + 8) = *(const uint4*)&T[n_l][cs + 8];
    }
}

// ---------------------------------------------------------------------------
// Kernel 0b: cast qkv_w [1536*256] and proj_w [256*512] fp32 -> bf16.
// ---------------------------------------------------------------------------
__global__ __launch_bounds__(256)
void cast_w(const float* __restrict__ qw, const float* __restrict__ pw,
            ushort* __restrict__ qwb, ushort* __restrict__ pwb)
{
    const int i = blockIdx.x * 256 + threadIdx.x;   // one float4 each
    const int nq4 = (1536 * 256) / 4;               // 98304
    const float* src; ushort* dst; int j;
    if (i < nq4) { src = qw; dst = qwb; j = i; }
    else         { src = pw; dst = pwb; j = i - nq4; }
    const float4 v = *(const float4*)(src + 4 * j);
    ushort4 u; u.x = f2b(v.x); u.y = f2b(v.y); u.z = f2b(v.z); u.w = f2b(v.w);
    *(ushort4*)(dst + 4 * j) = u;
}

// ---------------------------------------------------------------------------
// Kernel 1: QKV GEMM, bf16 MFMA 16x16x32. A = w [o][c], B = xb [n][c].
// 128(o) x 128(n) tile, 4 waves in 2x2 of 64x64, K=256 in 8 steps of 32.
// LDS stride 40 shorts (80B = 5x16B: aligned b128 frags, 2-way banks = free).
// Epilogue: C -> LDS [n][o] bf16 (bias+scale applied) -> coalesced 16B
// stores into q/k/v [bh][n][64] layout. q pre-scaled by 0.125.
// ---------------------------------------------------------------------------
__global__ __launch_bounds__(256)
void qkv_gemm(const ushort* __restrict__ xb, const ushort* __restrict__ wb,
              const float* __restrict__ bias,
              ushort* __restrict__ qb, ushort* __restrict__ kb, ushort* __restrict__ vb)
{
    __shared__ ushort lds[17408];        // 34.8 KB; staging + epilogue alias
    ushort* As = lds;                    // [128 o][40]
    ushort* Bs = lds + 5120;             // [128 n][40]

    const int t = threadIdx.x;
    const int w = t >> 6, lane = t & 63, quad = lane >> 4, ln = lane & 15;
    const int n0 = blockIdx.x * 128;
    const int o0 = blockIdx.y * 128;
    const int b  = blockIdx.z;
    const int ow = (w & 1) * 64, nw = (w >> 1) * 64;

    f4 acc[4][4];
#pragma unroll
    for (int i = 0; i < 4; ++i)
#pragma unroll
        for (int j = 0; j < 4; ++j) acc[i][j] = (f4){0.f, 0.f, 0.f, 0.f};

    const int r = t >> 1, hh = (t & 1) * 16;
    for (int k0 = 0; k0 < Cin; k0 += 32) {
        __syncthreads();
        {   // stage A (w) and B (xb): 32 shorts per row, 2 uint4 per thread each
            const ushort* sa = &wb[(o0 + r) * Cin + k0 + hh];
            *(uint4*)&As[r * 40 + hh]     = *(const uint4*)sa;
            *(uint4*)&As[r * 40 + hh + 8] = *(const uint4*)(sa + 8);
            const ushort* sb = &xb[((b << 10) + n0 + r) * Cin + k0 + hh];
            *(uint4*)&Bs[r * 40 + hh]     = *(const uint4*)sb;
            *(uint4*)&Bs[r * 40 + hh + 8] = *(const uint4*)(sb + 8);
        }
        __syncthreads();
        short8 af[4], bf[4];
#pragma unroll
        for (int ot = 0; ot < 4; ++ot)
            af[ot] = *(const short8*)&As[(ow + ot * 16 + ln) * 40 + quad * 8];
#pragma unroll
        for (int nt = 0; nt < 4; ++nt)
            bf[nt] = *(const short8*)&Bs[(nw + nt * 16 + ln) * 40 + quad * 8];
#pragma unroll
        for (int ot = 0; ot < 4; ++ot)
#pragma unroll
            for (int nt = 0; nt < 4; ++nt)
                acc[ot][nt] = __builtin_amdgcn_mfma_f32_16x16x32_bf16(
                    af[ot], bf[nt], acc[ot][nt], 0, 0, 0);
    }

    __syncthreads();                     // staging reads done; alias as Ct
    ushort* Ct = lds;                    // [128 n][136 o-stride]
    const float sc = (o0 < 512) ? 0.125f : 1.0f;   // q pre-scale (exact pow2)
#pragma unroll
    for (int ot = 0; ot < 4; ++ot) {
        float bs[4];
#pragma unroll
        for (int rg = 0; rg < 4; ++rg)
            bs[rg] = bias[o0 + ow + ot * 16 + quad * 4 + rg];
#pragma unroll
        for (int nt = 0; nt < 4; ++nt) {
            ushort4 u;
            u.x = f2b((acc[ot][nt][0] + bs[0]) * sc);
            u.y = f2b((acc[ot][nt][1] + bs[1]) * sc);
            u.z = f2b((acc[ot][nt][2] + bs[2]) * sc);
            u.w = f2b((acc[ot][nt][3] + bs[3]) * sc);
            *(ushort4*)&Ct[(nw + nt * 16 + ln) * 136 + ow + ot * 16 + quad * 4] = u;
        }
    }
    __syncthreads();

    // coalesced writeout: row n = t>>1, o-half hf = t&1 (one head = 64 ch)
    ushort* dst; int obase;
    if (o0 < 512)       { dst = qb; obase = o0; }
    else if (o0 < 1024) { dst = kb; obase = o0 - 512; }
    else                { dst = vb; obase = o0 - 1024; }
    {
        const int rn = t >> 1, hf = t & 1;
        const int bh = b * 8 + (obase >> 6) + hf;
        ushort* drow = &dst[(bh * Np + n0 + rn) << 6];
        const ushort* srow = &Ct[rn * 136 + hf * 64];
#pragma unroll
        for (int s = 0; s < 8; ++s)   // 8 x 8 ushorts = full 64-ch head row
            *(uint4*)(drow + s * 8) = *(const uint4*)(srow + s * 8);
    }
}

// ---------------------------------------------------------------------------
// Kernel 2: causal flash attention, bf16 MFMA (16x16x32), fp32 softmax.
// One block per (bh, 64-row q-tile); wave w owns q rows [w*16, w*16+16).
// Output bf16 (feeds proj MFMA staging directly).
// ---------------------------------------------------------------------------
__global__ __launch_bounds__(256, 4)
void attn(const ushort* __restrict__ qb, const ushort* __restrict__ kb,
          const ushort* __restrict__ vb, ushort* __restrict__ ob)
{
    __shared__ ushort Qs[64 * 72];   // [q][d]
    __shared__ ushort Ks[64 * 72];   // [k][d]
    __shared__ ushort Vt[64 * 72];   // [d][k] (transposed)
    __shared__ ushort Ps[64 * 72];   // [q][k]

    const int t    = threadIdx.x;
    const int w    = t >> 6;
    const int lane = t & 63;
    const int quad = lane >> 4;
    const int ln   = lane & 15;
    const int bh   = blockIdx.x & 127;
    const int qt   = 15 - (blockIdx.x >> 7);   // heavy blocks first
    const int q0   = qt * 64;

    {   // stage Q tile (pre-scaled by 0.125 in qkv epilogue)
        const int r = t & 63, seg = t >> 6;
        const ushort* src = &qb[((bh * Np + q0 + r) << 6) + seg * 16];
        *(uint4*)&Qs[r * 72 + seg * 16]     = *(const uint4*)src;
        *(uint4*)&Qs[r * 72 + seg * 16 + 8] = *(const uint4*)(src + 8);
    }
    __syncthreads();

    short8 qa0 = *(const short8*)&Qs[(w * 16 + ln) * 72 + quad * 8];
    short8 qa1 = *(const short8*)&Qs[(w * 16 + ln) * 72 + 32 + quad * 8];

    f4 o[4];
#pragma unroll
    for (int nt = 0; nt < 4; ++nt) o[nt] = (f4){0.f, 0.f, 0.f, 0.f};
    float mrun[4], lrun[4];
#pragma unroll
    for (int rg = 0; rg < 4; ++rg) { mrun[rg] = -INFINITY; lrun[rg] = 0.f; }

    for (int kt = 0; kt <= qt; ++kt) {
        __syncthreads();
        {   // stage K [k][d] and V transposed [d][k]
            const int r = t & 63, seg = t >> 6;
            const int gbase = ((bh * Np + kt * 64 + r) << 6) + seg * 16;
            *(uint4*)&Ks[r * 72 + seg * 16]     = *(const uint4*)&kb[gbase];
            *(uint4*)&Ks[r * 72 + seg * 16 + 8] = *(const uint4*)&kb[gbase + 8];
            ushort tmp[16];
            *(uint4*)&tmp[0] = *(const uint4*)&vb[gbase];
            *(uint4*)&tmp[8] = *(const uint4*)&vb[gbase + 8];
#pragma unroll
            for (int e = 0; e < 16; ++e) Vt[(seg * 16 + e) * 72 + r] = tmp[e];
        }
        __syncthreads();

        // S = Q K^T
        f4 s[4];
#pragma unroll
        for (int nt = 0; nt < 4; ++nt) s[nt] = (f4){0.f, 0.f, 0.f, 0.f};
#pragma unroll
        for (int nt = 0; nt < 4; ++nt) {
            short8 b0 = *(const short8*)&Ks[(nt * 16 + ln) * 72 + quad * 8];
            short8 b1 = *(const short8*)&Ks[(nt * 16 + ln) * 72 + 32 + quad * 8];
            s[nt] = __builtin_amdgcn_mfma_f32_16x16x32_bf16(qa0, b0, s[nt], 0, 0, 0);
            s[nt] = __builtin_amdgcn_mfma_f32_16x16x32_bf16(qa1, b1, s[nt], 0, 0, 0);
        }

        if (kt == qt) {   // causal mask on diagonal tile
            const int qr = w * 16 + quad * 4;
#pragma unroll
            for (int nt = 0; nt < 4; ++nt) {
                const int kc = nt * 16 + ln;
#pragma unroll
                for (int rg = 0; rg < 4; ++rg)
                    if (kc > qr + rg) s[nt][rg] = -INFINITY;
            }
        }

        float mx[4];
#pragma unroll
        for (int rg = 0; rg < 4; ++rg)
            mx[rg] = fmaxf(fmaxf(s[0][rg], s[1][rg]), fmaxf(s[2][rg], s[3][rg]));
#pragma unroll
        for (int off = 1; off < 16; off <<= 1)
#pragma unroll
            for (int rg = 0; rg < 4; ++rg)
                mx[rg] = fmaxf(mx[rg], __shfl_xor(mx[rg], off));

        float al[4];
#pragma unroll
        for (int rg = 0; rg < 4; ++rg) {
            const float mn = fmaxf(mrun[rg], mx[rg]);
            al[rg]   = __expf(mrun[rg] - mn);
            mrun[rg] = mn;
        }

        float rs[4] = {0.f, 0.f, 0.f, 0.f};
        const int prow = (w * 16 + quad * 4) * 72 + ln;
#pragma unroll
        for (int nt = 0; nt < 4; ++nt)
#pragma unroll
            for (int rg = 0; rg < 4; ++rg) {
                const float p = __expf(s[nt][rg] - mrun[rg]);
                Ps[prow + rg * 72 + nt * 16] = f2b(p);
                rs[rg] += p;
            }
#pragma unroll
        for (int off = 1; off < 16; off <<= 1)
#pragma unroll
            for (int rg = 0; rg < 4; ++rg) rs[rg] += __shfl_xor(rs[rg], off);

#pragma unroll
        for (int rg = 0; rg < 4; ++rg) lrun[rg] = lrun[rg] * al[rg] + rs[rg];
#pragma unroll
        for (int nt = 0; nt < 4; ++nt)
#pragma unroll
            for (int rg = 0; rg < 4; ++rg) o[nt][rg] *= al[rg];

        // O += P V (wave-private P strip, no barrier needed)
#pragma unroll
        for (int ks = 0; ks < 2; ++ks) {
            short8 pa = *(const short8*)&Ps[(w * 16 + ln) * 72 + ks * 32 + quad * 8];
#pragma unroll
            for (int nt = 0; nt < 4; ++nt) {
                short8 vf = *(const short8*)&Vt[(nt * 16 + ln) * 72 + ks * 32 + quad * 8];
                o[nt] = __builtin_amdgcn_mfma_f32_16x16x32_bf16(pa, vf, o[nt], 0, 0, 0);
            }
        }
    }

    float inv[4];
#pragma unroll
    for (int rg = 0; rg < 4; ++rg) inv[rg] = 1.0f / lrun[rg];
#pragma unroll
    for (int rg = 0; rg < 4; ++rg) {
        const int rr = q0 + w * 16 + quad * 4 + rg;
#pragma unroll
        for (int nt = 0; nt < 4; ++nt)
            ob[((bh * Np + rr) << 6) + nt * 16 + ln] = f2b(o[nt][rg] * inv[rg]);
    }
}

// ---------------------------------------------------------------------------
// Kernel 3: projection GEMM, bf16 MFMA. A = pw [o][v], B = attn-out
// (head-interleaved [bh][n][64]). 128(o) x 128(n) tile, K=512 in 16 steps.
// ---------------------------------------------------------------------------
__global__ __launch_bounds__(256)
void proj_gemm(const ushort* __restrict__ obuf, const ushort* __restrict__ pwb,
               const float* __restrict__ bias, float* __restrict__ out)
{
    __shared__ ushort As[128 * 40];   // pw [o][k]
    __shared__ ushort Bs[128 * 40];   // attn-out [n][k]

    const int t = threadIdx.x;
    const int w = t >> 6, lane = t & 63, quad = lane >> 4, ln = lane & 15;
    const int n0 = blockIdx.x * 128;
    const int o0 = blockIdx.y * 128;
    const int b  = blockIdx.z;
    const int ow = (w & 1) * 64, nw = (w >> 1) * 64;

    f4 acc[4][4];
#pragma unroll
    for (int i = 0; i < 4; ++i)
#pragma unroll
        for (int j = 0; j < 4; ++j) acc[i][j] = (f4){0.f, 0.f, 0.f, 0.f};

    const int r = t >> 1, hh = (t & 1) * 16;
    for (int k0 = 0; k0 < 512; k0 += 32) {
        __syncthreads();
        {
            const ushort* sa = &pwb[(o0 + r) * 512 + k0 + hh];
            *(uint4*)&As[r * 40 + hh]     = *(const uint4*)sa;
            *(uint4*)&As[r * 40 + hh + 8] = *(const uint4*)(sa + 8);
            const int head = k0 >> 6, kc = k0 & 63;
            const ushort* sb = &obuf[(((b * 8 + head) * Np + n0 + r) << 6) + kc + hh];
            *(uint4*)&Bs[r * 40 + hh]     = *(const uint4*)sb;
            *(uint4*)&Bs[r * 40 + hh + 8] = *(const uint4*)(sb + 8);
        }
        __syncthreads();
        short8 af[4], bf[4];
#pragma unroll
        for (int ot = 0; ot < 4; ++ot)
            af[ot] = *(const short8*)&As[(ow + ot * 16 + ln) * 40 + quad * 8];
#pragma unroll
        for (int nt = 0; nt < 4; ++nt)
            bf[nt] = *(const short8*)&Bs[(nw + nt * 16 + ln) * 40 + quad * 8];
#pragma unroll
        for (int ot = 0; ot < 4; ++ot)
#pragma unroll
            for (int nt = 0; nt < 4; ++nt)
                acc[ot][nt] = __builtin_amdgcn_mfma_f32_16x16x32_bf16(
                    af[ot], bf[nt], acc[ot][nt], 0, 0, 0);
    }

    // epilogue: direct fp32 stores (16-lane 64B segments), bias added
#pragma unroll
    for (int ot = 0; ot < 4; ++ot) {
        float bs[4];
#pragma unroll
        for (int rg = 0; rg < 4; ++rg)
            bs[rg] = bias[o0 + ow + ot * 16 + quad * 4 + rg];
#pragma unroll
        for (int rg = 0; rg < 4; ++rg) {
            const int oo = o0 + ow + ot * 16 + quad * 4 + rg;
            float* drow = &out[((b << 8) + oo) << 10];
#pragma unroll
            for (int nt = 0; nt < 4; ++nt)
                drow[n0 + nw + nt * 16 + ln] = acc[ot][nt][rg] + bs[rg];
        }
    }
}

// ---------------------------------------------------------------------------
extern "C" void kernel_launch(void* const* d_in, const int* in_sizes, int n_in,
                              void* d_out, int out_size, void* d_ws, size_t ws_size,
                              hipStream_t stream)
{
    const float* x   = (const float*)d_in[0];   // [16,256,1024]
    const float* qw  = (const float*)d_in[1];   // [1536,256]
    const float* qbb = (const float*)d_in[2];   // [1536]
    const float* pw  = (const float*)d_in[3];   // [256,512]
    const float* pb  = (const float*)d_in[4];   // [256]
    float* out = (float*)d_out;                 // [16,256,1024]

    // workspace (all bf16): q/k/v/attn-out [128][1024][64] = 16.8 MB each,
    // xb [16][1024][256] = 8.4 MB, qwb 0.79 MB, pwb 0.26 MB. total ~77 MB.
    const size_t per = (size_t)Bsz * 8 * Np * 64;
    ushort* qbuf = (ushort*)d_ws;
    ushort* kbuf = qbuf + per;
    ushort* vbuf = kbuf + per;
    ushort* obuf = vbuf + per;
    ushort* xb   = obuf + per;
    ushort* qwb  = xb + (size_t)Bsz * Np * Cin;
    ushort* pwb  = qwb + 1536 * Cin;

    cast_x<<<dim3(16, 4, Bsz), 256, 0, stream>>>(x, xb);
    cast_w<<<dim3(512), 256, 0, stream>>>(qw, pw, qwb, pwb);
    qkv_gemm<<<dim3(8, 12, Bsz), 256, 0, stream>>>(xb, qwb, qbb, qbuf, kbuf, vbuf);
    attn<<<dim3(128 * 16), 256, 0, stream>>>(qbuf, kbuf, vbuf, obuf);
    proj_gemm<<<dim3(8, 2, Bsz), 256, 0, stream>>>(obuf, pwb, pb, out);
}

// Round 5
// 180.664 us; speedup vs baseline: 3.8871x; 1.0852x over previous
//
#include <hip/hip_runtime.h>
#include <math.h>

// Problem constants: B=16, C_in=256, H=W=32 -> N=1024, qkv_out=1536,
// HEAD=8, dh=dv=64, V_DIM=512, OUT_CH=256.
static constexpr int Bsz = 16;
static constexpr int Np  = 1024;
static constexpr int Cin = 256;

typedef __attribute__((ext_vector_type(8))) short short8;  // 8 bf16 = 4 VGPR
typedef __attribute__((ext_vector_type(4))) float f4;      // mfma acc

// fp32 -> bf16 round-to-nearest-even
__device__ __forceinline__ unsigned short f2b(float f) {
    union { float fp; unsigned int u; } v; v.fp = f;
    unsigned int r = v.u + 0x7fffu + ((v.u >> 16) & 1u);
    return (unsigned short)(r >> 16);
}

// ---------------------------------------------------------------------------
// Kernel 0a: cast+transpose x [b][c][n] fp32 -> xb [b][n][c] bf16.
// ---------------------------------------------------------------------------
__global__ __launch_bounds__(256)
void cast_x(const float* __restrict__ x, ushort* __restrict__ xb)
{
    __shared__ ushort T[64][72];   // [n][c]
    const int t = threadIdx.x;
    const int n0 = blockIdx.x * 64, c0 = blockIdx.y * 64, b = blockIdx.z;

    {   // read 64c x 64n, convert, transposed scatter into LDS
        const int c_l = t >> 2, ns = (t & 3) * 16;
        const float* src = &x[((b * Cin + c0 + c_l) << 10) + n0 + ns];
#pragma unroll
        for (int i = 0; i < 4; ++i) {
            const float4 v = *(const float4*)(src + 4 * i);
            T[ns + 4 * i + 0][c_l] = f2b(v.x);
            T[ns + 4 * i + 1][c_l] = f2b(v.y);
            T[ns + 4 * i + 2][c_l] = f2b(v.z);
            T[ns + 4 * i + 3][c_l] = f2b(v.w);
        }
    }
    __syncthreads();
    {   // write rows of c (contiguous) to xb
        const int n_l = t >> 2, cs = (t & 3) * 16;
        ushort* dst = &xb[((b << 10) + n0 + n_l) * Cin + c0 + cs];
        *(uint4*)dst       = *(const uint4*)&T[n_l][cs];
        *(uint4*)(dst + 8) = *(const uint4*)&T[n_l][cs + 8];
    }
}

// ---------------------------------------------------------------------------
// Kernel 0b: cast qkv_w and proj_w fp32 -> bf16.
// ---------------------------------------------------------------------------
__global__ __launch_bounds__(256)
void cast_w(const float* __restrict__ qw, const float* __restrict__ pw,
            ushort* __restrict__ qwb, ushort* __restrict__ pwb)
{
    const int i = blockIdx.x * 256 + threadIdx.x;   // one float4 each
    const int nq4 = (1536 * 256) / 4;
    const float* src; ushort* dst; int j;
    if (i < nq4) { src = qw; dst = qwb; j = i; }
    else         { src = pw; dst = pwb; j = i - nq4; }
    const float4 v = *(const float4*)(src + 4 * j);
    ushort4 u; u.x = f2b(v.x); u.y = f2b(v.y); u.z = f2b(v.z); u.w = f2b(v.w);
    *(ushort4*)(dst + 4 * j) = u;
}

// ---------------------------------------------------------------------------
// Kernel 1: QKV GEMM, bf16 MFMA 16x16x32.
// Q/K o-tiles: C = W*X -> Ct [n][o] -> q/k [bh][n][64] (q pre-scaled 0.125).
// V  o-tiles: operands swapped (C^T = X*W) so epilogue writes Ct [o][n]
// vectorized, then vbuf TRANSPOSED [bh][d][n] -- attn then stages Vt with
// vector copies instead of a 16x-repeated scalar LDS transpose.
// ---------------------------------------------------------------------------
__global__ __launch_bounds__(256)
void qkv_gemm(const ushort* __restrict__ xb, const ushort* __restrict__ wb,
              const float* __restrict__ bias,
              ushort* __restrict__ qb, ushort* __restrict__ kb, ushort* __restrict__ vb)
{
    __shared__ ushort lds[17408];        // 34.8 KB; staging + epilogue alias
    ushort* As = lds;                    // [128 o][40]
    ushort* Bs = lds + 5120;             // [128 n][40]

    const int t = threadIdx.x;
    const int w = t >> 6, lane = t & 63, quad = lane >> 4, ln = lane & 15;
    const int n0 = blockIdx.x * 128;
    const int o0 = blockIdx.y * 128;
    const int b  = blockIdx.z;
    const int ow = (w & 1) * 64, nw = (w >> 1) * 64;
    const bool vpath = (o0 >= 1024);

    f4 acc[4][4];
#pragma unroll
    for (int i = 0; i < 4; ++i)
#pragma unroll
        for (int j = 0; j < 4; ++j) acc[i][j] = (f4){0.f, 0.f, 0.f, 0.f};

    const int r = t >> 1, hh = (t & 1) * 16;
    for (int k0 = 0; k0 < Cin; k0 += 32) {
        __syncthreads();
        {   // stage A (w) and B (xb)
            const ushort* sa = &wb[(o0 + r) * Cin + k0 + hh];
            *(uint4*)&As[r * 40 + hh]     = *(const uint4*)sa;
            *(uint4*)&As[r * 40 + hh + 8] = *(const uint4*)(sa + 8);
            const ushort* sb = &xb[((b << 10) + n0 + r) * Cin + k0 + hh];
            *(uint4*)&Bs[r * 40 + hh]     = *(const uint4*)sb;
            *(uint4*)&Bs[r * 40 + hh + 8] = *(const uint4*)(sb + 8);
        }
        __syncthreads();
        short8 af[4], bf[4];
#pragma unroll
        for (int ot = 0; ot < 4; ++ot)
            af[ot] = *(const short8*)&As[(ow + ot * 16 + ln) * 40 + quad * 8];
#pragma unroll
        for (int nt = 0; nt < 4; ++nt)
            bf[nt] = *(const short8*)&Bs[(nw + nt * 16 + ln) * 40 + quad * 8];
        if (!vpath) {   // acc[ot][nt]: row = o, col = n
#pragma unroll
            for (int ot = 0; ot < 4; ++ot)
#pragma unroll
                for (int nt = 0; nt < 4; ++nt)
                    acc[ot][nt] = __builtin_amdgcn_mfma_f32_16x16x32_bf16(
                        af[ot], bf[nt], acc[ot][nt], 0, 0, 0);
        } else {        // acc[nt][ot]: row = n, col = o (transposed C)
#pragma unroll
            for (int nt = 0; nt < 4; ++nt)
#pragma unroll
                for (int ot = 0; ot < 4; ++ot)
                    acc[nt][ot] = __builtin_amdgcn_mfma_f32_16x16x32_bf16(
                        bf[nt], af[ot], acc[nt][ot], 0, 0, 0);
        }
    }

    __syncthreads();                     // staging reads done; alias lds
    if (!vpath) {
        // ---- Q/K epilogue: Ct [n][136 o-stride], vectorized both ways ----
        ushort* Ct = lds;
        const float sc = (o0 < 512) ? 0.125f : 1.0f;
#pragma unroll
        for (int ot = 0; ot < 4; ++ot) {
            float bs[4];
#pragma unroll
            for (int rg = 0; rg < 4; ++rg)
                bs[rg] = bias[o0 + ow + ot * 16 + quad * 4 + rg];
#pragma unroll
            for (int nt = 0; nt < 4; ++nt) {
                ushort4 u;
                u.x = f2b((acc[ot][nt][0] + bs[0]) * sc);
                u.y = f2b((acc[ot][nt][1] + bs[1]) * sc);
                u.z = f2b((acc[ot][nt][2] + bs[2]) * sc);
                u.w = f2b((acc[ot][nt][3] + bs[3]) * sc);
                *(ushort4*)&Ct[(nw + nt * 16 + ln) * 136 + ow + ot * 16 + quad * 4] = u;
            }
        }
        __syncthreads();
        ushort* dst; int obase;
        if (o0 < 512) { dst = qb; obase = o0; }
        else          { dst = kb; obase = o0 - 512; }
        const int rn = t >> 1, hf = t & 1;
        const int bh = b * 8 + (obase >> 6) + hf;
        ushort* drow = &dst[(bh * Np + n0 + rn) << 6];
        const ushort* srow = &Ct[rn * 136 + hf * 64];
#pragma unroll
        for (int s = 0; s < 8; ++s)
            *(uint4*)(drow + s * 8) = *(const uint4*)(srow + s * 8);
    } else {
        // ---- V epilogue: Ct [o][136 n-stride] (rows = d), then [bh][d][n] ----
        ushort* Ct = lds;
#pragma unroll
        for (int ot = 0; ot < 4; ++ot) {
            const float bo = bias[o0 + ow + ot * 16 + ln];
#pragma unroll
            for (int nt = 0; nt < 4; ++nt) {
                ushort4 u;
                u.x = f2b(acc[nt][ot][0] + bo);
                u.y = f2b(acc[nt][ot][1] + bo);
                u.z = f2b(acc[nt][ot][2] + bo);
                u.w = f2b(acc[nt][ot][3] + bo);
                *(ushort4*)&Ct[(ow + ot * 16 + ln) * 136 + nw + nt * 16 + quad * 4] = u;
            }
        }
        __syncthreads();
        const int o_l = t >> 1, nh = (t & 1) * 64;
        const int bh = b * 8 + ((o0 - 1024) >> 6) + (o_l >> 6);
        ushort* drow = &vb[((size_t)bh << 16) + ((o_l & 63) << 10) + n0 + nh];
        const ushort* srow = &Ct[o_l * 136 + nh];
#pragma unroll
        for (int s = 0; s < 8; ++s)
            *(uint4*)(drow + s * 8) = *(const uint4*)(srow + s * 8);
    }
}

// ---------------------------------------------------------------------------
// Kernel 2: causal flash attention, bf16 MFMA, fp32 softmax.
// Computes S^T = K*Q^T (rows = k, lane-cols = q): softmax state is one
// scalar per lane; P store to A-layout [q][k] is 4x ushort4 (reg index
// contiguous in k); V arrives pre-transposed [bh][d][n] so Vt staging is
// pure vector copies. alpha / 1/l reach O rows (quad*4+rg) via 4 shuffles.
// ---------------------------------------------------------------------------
__global__ __launch_bounds__(256, 4)
void attn(const ushort* __restrict__ qb, const ushort* __restrict__ kb,
          const ushort* __restrict__ vt, ushort* __restrict__ ob)
{
    __shared__ ushort Qs[64 * 72];   // [q][d]
    __shared__ ushort Ks[64 * 72];   // [k][d]
    __shared__ ushort Vt[64 * 72];   // [d][k]
    __shared__ ushort Ps[64 * 72];   // [q][k]

    const int t    = threadIdx.x;
    const int w    = t >> 6;
    const int lane = t & 63;
    const int quad = lane >> 4;
    const int ln   = lane & 15;
    const int bh   = blockIdx.x & 127;
    const int qt   = 15 - (blockIdx.x >> 7);   // heavy blocks first
    const int q0   = qt * 64;

    {   // stage Q tile (pre-scaled by 0.125 in qkv epilogue)
        const int r = t & 63, seg = t >> 6;
        const ushort* src = &qb[((bh * Np + q0 + r) << 6) + seg * 16];
        *(uint4*)&Qs[r * 72 + seg * 16]     = *(const uint4*)src;
        *(uint4*)&Qs[r * 72 + seg * 16 + 8] = *(const uint4*)(src + 8);
    }
    __syncthreads();

    // Q B-frags for this wave's 16-row strip (reused over all k-tiles)
    const short8 qa0 = *(const short8*)&Qs[(w * 16 + ln) * 72 + quad * 8];
    const short8 qa1 = *(const short8*)&Qs[(w * 16 + ln) * 72 + 32 + quad * 8];

    f4 o_[4];
#pragma unroll
    for (int nt = 0; nt < 4; ++nt) o_[nt] = (f4){0.f, 0.f, 0.f, 0.f};
    float mrun = -INFINITY, lrun = 0.f;   // state for q = q0 + w*16 + ln

    for (int kt = 0; kt <= qt; ++kt) {
        __syncthreads();
        {   // stage K [k][d] (vector) and Vt [d][k] (vector, pre-transposed)
            const int r = t & 63, seg = t >> 6;
            const ushort* sk = &kb[((bh * Np + kt * 64 + r) << 6) + seg * 16];
            *(uint4*)&Ks[r * 72 + seg * 16]     = *(const uint4*)sk;
            *(uint4*)&Ks[r * 72 + seg * 16 + 8] = *(const uint4*)(sk + 8);
            const int dd = t >> 2, c = (t & 3) * 16;
            const ushort* sv = &vt[((size_t)bh << 16) + (dd << 10) + kt * 64 + c];
            *(uint4*)&Vt[dd * 72 + c]     = *(const uint4*)sv;
            *(uint4*)&Vt[dd * 72 + c + 8] = *(const uint4*)(sv + 8);
        }
        __syncthreads();

        const bool diag = (kt == qt);

        // ---- S^T = K Q^T : rows kcol = mt*16+quad*4+rg, col q = ln
        f4 st[4];
#pragma unroll
        for (int mt = 0; mt < 4; ++mt) st[mt] = (f4){0.f, 0.f, 0.f, 0.f};
#pragma unroll
        for (int mt = 0; mt < 4; ++mt) {
            if (diag && mt > w) continue;   // fully-masked tile (wave-uniform)
            const short8 ka0 = *(const short8*)&Ks[(mt * 16 + ln) * 72 + quad * 8];
            const short8 ka1 = *(const short8*)&Ks[(mt * 16 + ln) * 72 + 32 + quad * 8];
            st[mt] = __builtin_amdgcn_mfma_f32_16x16x32_bf16(ka0, qa0, st[mt], 0, 0, 0);
            st[mt] = __builtin_amdgcn_mfma_f32_16x16x32_bf16(ka1, qa1, st[mt], 0, 0, 0);
        }

        if (diag) {   // mask kcol > qrow
            const int qrow = w * 16 + ln;
#pragma unroll
            for (int mt = 0; mt < 4; ++mt)
#pragma unroll
                for (int rg = 0; rg < 4; ++rg)
                    if (mt * 16 + quad * 4 + rg > qrow) st[mt][rg] = -INFINITY;
        }

        // ---- online softmax: scalar state per lane, reduce across quads
        float mx = -INFINITY;
#pragma unroll
        for (int mt = 0; mt < 4; ++mt)
#pragma unroll
            for (int rg = 0; rg < 4; ++rg) mx = fmaxf(mx, st[mt][rg]);
        mx = fmaxf(mx, __shfl_xor(mx, 16));
        mx = fmaxf(mx, __shfl_xor(mx, 32));

        const float mn = fmaxf(mrun, mx);
        const float al = __expf(mrun - mn);   // first tile: expf(-inf)=0
        mrun = mn;

        float rs = 0.f;
        const int prow = (w * 16 + ln) * 72;
#pragma unroll
        for (int mt = 0; mt < 4; ++mt) {
            float p0 = __expf(st[mt][0] - mn), p1 = __expf(st[mt][1] - mn);
            float p2 = __expf(st[mt][2] - mn), p3 = __expf(st[mt][3] - mn);
            rs += (p0 + p1) + (p2 + p3);
            ushort4 u; u.x = f2b(p0); u.y = f2b(p1); u.z = f2b(p2); u.w = f2b(p3);
            *(ushort4*)&Ps[prow + mt * 16 + quad * 4] = u;
        }
        rs += __shfl_xor(rs, 16);
        rs += __shfl_xor(rs, 32);
        lrun = lrun * al + rs;

        float alr[4];   // alpha for O rows quad*4+rg (fetch from ln=that row)
#pragma unroll
        for (int rg = 0; rg < 4; ++rg) alr[rg] = __shfl(al, quad * 4 + rg);
#pragma unroll
        for (int nt = 0; nt < 4; ++nt)
#pragma unroll
            for (int rg = 0; rg < 4; ++rg) o_[nt][rg] *= alr[rg];

        // ---- O += P V (wave-private P rows; Vt pre-transposed)
#pragma unroll
        for (int ks = 0; ks < 2; ++ks) {
            if (diag && w * 16 + 15 < ks * 32) continue;   // zero P half
            const short8 pa = *(const short8*)&Ps[prow + ks * 32 + quad * 8];
#pragma unroll
            for (int nt = 0; nt < 4; ++nt) {
                const short8 vf = *(const short8*)&Vt[(nt * 16 + ln) * 72 + ks * 32 + quad * 8];
                o_[nt] = __builtin_amdgcn_mfma_f32_16x16x32_bf16(pa, vf, o_[nt], 0, 0, 0);
            }
        }
    }

    // ---- epilogue: O / l -> bf16 ob [bh][q][64]
    const float linv = 1.0f / lrun;
    float lr[4];
#pragma unroll
    for (int rg = 0; rg < 4; ++rg) lr[rg] = __shfl(linv, quad * 4 + rg);
#pragma unroll
    for (int rg = 0; rg < 4; ++rg) {
        const int rr = q0 + w * 16 + quad * 4 + rg;
#pragma unroll
        for (int nt = 0; nt < 4; ++nt)
            ob[((bh * Np + rr) << 6) + nt * 16 + ln] = f2b(o_[nt][rg] * lr[rg]);
    }
}

// ---------------------------------------------------------------------------
// Kernel 3: projection GEMM, bf16 MFMA. A = pw [o][v], B = attn-out
// (head-interleaved [bh][n][64]). 128(o) x 128(n) tile, K=512 in 16 steps.
// ---------------------------------------------------------------------------
__global__ __launch_bounds__(256)
void proj_gemm(const ushort* __restrict__ obuf, const ushort* __restrict__ pwb,
               const float* __restrict__ bias, float* __restrict__ out)
{
    __shared__ ushort As[128 * 40];   // pw [o][k]
    __shared__ ushort Bs[128 * 40];   // attn-out [n][k]

    const int t = threadIdx.x;
    const int w = t >> 6, lane = t & 63, quad = lane >> 4, ln = lane & 15;
    const int n0 = blockIdx.x * 128;
    const int o0 = blockIdx.y * 128;
    const int b  = blockIdx.z;
    const int ow = (w & 1) * 64, nw = (w >> 1) * 64;

    f4 acc[4][4];
#pragma unroll
    for (int i = 0; i < 4; ++i)
#pragma unroll
        for (int j = 0; j < 4; ++j) acc[i][j] = (f4){0.f, 0.f, 0.f, 0.f};

    const int r = t >> 1, hh = (t & 1) * 16;
    for (int k0 = 0; k0 < 512; k0 += 32) {
        __syncthreads();
        {
            const ushort* sa = &pwb[(o0 + r) * 512 + k0 + hh];
            *(uint4*)&As[r * 40 + hh]     = *(const uint4*)sa;
            *(uint4*)&As[r * 40 + hh + 8] = *(const uint4*)(sa + 8);
            const int head = k0 >> 6, kc = k0 & 63;
            const ushort* sb = &obuf[(((b * 8 + head) * Np + n0 + r) << 6) + kc + hh];
            *(uint4*)&Bs[r * 40 + hh]     = *(const uint4*)sb;
            *(uint4*)&Bs[r * 40 + hh + 8] = *(const uint4*)(sb + 8);
        }
        __syncthreads();
        short8 af[4], bf[4];
#pragma unroll
        for (int ot = 0; ot < 4; ++ot)
            af[ot] = *(const short8*)&As[(ow + ot * 16 + ln) * 40 + quad * 8];
#pragma unroll
        for (int nt = 0; nt < 4; ++nt)
            bf[nt] = *(const short8*)&Bs[(nw + nt * 16 + ln) * 40 + quad * 8];
#pragma unroll
        for (int ot = 0; ot < 4; ++ot)
#pragma unroll
            for (int nt = 0; nt < 4; ++nt)
                acc[ot][nt] = __builtin_amdgcn_mfma_f32_16x16x32_bf16(
                    af[ot], bf[nt], acc[ot][nt], 0, 0, 0);
    }

    // epilogue: direct fp32 stores (16-lane 64B segments), bias added
#pragma unroll
    for (int ot = 0; ot < 4; ++ot) {
        float bs[4];
#pragma unroll
        for (int rg = 0; rg < 4; ++rg)
            bs[rg] = bias[o0 + ow + ot * 16 + quad * 4 + rg];
#pragma unroll
        for (int rg = 0; rg < 4; ++rg) {
            const int oo = o0 + ow + ot * 16 + quad * 4 + rg;
            float* drow = &out[((b << 8) + oo) << 10];
#pragma unroll
            for (int nt = 0; nt < 4; ++nt)
                drow[n0 + nw + nt * 16 + ln] = acc[ot][nt][rg] + bs[rg];
        }
    }
}

// ---------------------------------------------------------------------------
extern "C" void kernel_launch(void* const* d_in, const int* in_sizes, int n_in,
                              void* d_out, int out_size, void* d_ws, size_t ws_size,
                              hipStream_t stream)
{
    const float* x   = (const float*)d_in[0];   // [16,256,1024]
    const float* qw  = (const float*)d_in[1];   // [1536,256]
    const float* qbb = (const float*)d_in[2];   // [1536]
    const float* pw  = (const float*)d_in[3];   // [256,512]
    const float* pb  = (const float*)d_in[4];   // [256]
    float* out = (float*)d_out;                 // [16,256,1024]

    // workspace (all bf16): q/k [bh][n][64], v TRANSPOSED [bh][64][n],
    // attn-out [bh][n][64]; xb [b][n][c]; weights.
    const size_t per = (size_t)Bsz * 8 * Np * 64;
    ushort* qbuf = (ushort*)d_ws;
    ushort* kbuf = qbuf + per;
    ushort* vbuf = kbuf + per;
    ushort* obuf = vbuf + per;
    ushort* xb   = obuf + per;
    ushort* qwb  = xb + (size_t)Bsz * Np * Cin;
    ushort* pwb  = qwb + 1536 * Cin;

    cast_x<<<dim3(16, 4, Bsz), 256, 0, stream>>>(x, xb);
    cast_w<<<dim3(512), 256, 0, stream>>>(qw, pw, qwb, pwb);
    qkv_gemm<<<dim3(8, 12, Bsz), 256, 0, stream>>>(xb, qwb, qbb, qbuf, kbuf, vbuf);
    attn<<<dim3(128 * 16), 256, 0, stream>>>(qbuf, kbuf, vbuf, obuf);
    proj_gemm<<<dim3(8, 2, Bsz), 256, 0, stream>>>(obuf, pwb, pb, out);
}

// Round 6
// 164.765 us; speedup vs baseline: 4.2622x; 1.0965x over previous
//
#include <hip/hip_runtime.h>
#include <math.h>

// Problem constants: B=16, C_in=256, H=W=32 -> N=1024, qkv_out=1536,
// HEAD=8, dh=dv=64, V_DIM=512, OUT_CH=256.
static constexpr int Bsz = 16;
static constexpr int Np  = 1024;
static constexpr int Cin = 256;

typedef __attribute__((ext_vector_type(8))) short short8;  // 8 bf16 = 4 VGPR
typedef __attribute__((ext_vector_type(4))) float f4;      // mfma acc

// v_exp_f32 computes 2^x natively; use it without the log2e multiply.
#if defined(__has_builtin)
#if __has_builtin(__builtin_amdgcn_exp2f)
#define EXP2(x) __builtin_amdgcn_exp2f(x)
#else
#define EXP2(x) exp2f(x)
#endif
#else
#define EXP2(x) exp2f(x)
#endif

// q pre-scale: dh^-0.5 * log2(e), folded in fp32 BEFORE the single bf16
// rounding (same rounding error as any scale; scores exit QK^T in log2 domain)
#define QSCALE 0.18033688011112f

// fp32 -> bf16 round-to-nearest-even
__device__ __forceinline__ unsigned short f2b(float f) {
    union { float fp; unsigned int u; } v; v.fp = f;
    unsigned int r = v.u + 0x7fffu + ((v.u >> 16) & 1u);
    return (unsigned short)(r >> 16);
}

// ---------------------------------------------------------------------------
// Kernel 0: cast+transpose x [b][c][n] fp32 -> xb [b][n][c] bf16 (y<4),
// and cast qkv_w / proj_w fp32 -> bf16 (y==4). Single launch.
// ---------------------------------------------------------------------------
__global__ __launch_bounds__(256)
void cast_xw(const float* __restrict__ x, const float* __restrict__ qw,
             const float* __restrict__ pw, ushort* __restrict__ xb,
             ushort* __restrict__ qwb, ushort* __restrict__ pwb)
{
    const int t = threadIdx.x;
    if (blockIdx.y < 4) {
        __shared__ ushort T[64][72];   // [n][c]
        const int n0 = blockIdx.x * 64, c0 = blockIdx.y * 64, b = blockIdx.z;
        {   // read 64c x 64n, convert, transposed scatter into LDS
            const int c_l = t >> 2, ns = (t & 3) * 16;
            const float* src = &x[((b * Cin + c0 + c_l) << 10) + n0 + ns];
#pragma unroll
            for (int i = 0; i < 4; ++i) {
                const float4 v = *(const float4*)(src + 4 * i);
                T[ns + 4 * i + 0][c_l] = f2b(v.x);
                T[ns + 4 * i + 1][c_l] = f2b(v.y);
                T[ns + 4 * i + 2][c_l] = f2b(v.z);
                T[ns + 4 * i + 3][c_l] = f2b(v.w);
            }
        }
        __syncthreads();
        {   // write rows of c (contiguous) to xb
            const int n_l = t >> 2, cs = (t & 3) * 16;
            ushort* dst = &xb[((b << 10) + n0 + n_l) * Cin + c0 + cs];
            *(uint4*)dst       = *(const uint4*)&T[n_l][cs];
            *(uint4*)(dst + 8) = *(const uint4*)&T[n_l][cs + 8];
        }
    } else {
        // weights: 524288 floats total = 131072 float4; 256 blocks x 256 thr x 2
        const int nq4 = (1536 * Cin) / 4;
        const int base = ((blockIdx.z * 16 + blockIdx.x) * 256 + t) * 2;
#pragma unroll
        for (int g = 0; g < 2; ++g) {
            const int j = base + g;
            const float* src; ushort* dst; int jj;
            if (j < nq4) { src = qw; dst = qwb; jj = j; }
            else         { src = pw; dst = pwb; jj = j - nq4; }
            const float4 v = *(const float4*)(src + 4 * jj);
            ushort4 u; u.x = f2b(v.x); u.y = f2b(v.y); u.z = f2b(v.z); u.w = f2b(v.w);
            *(ushort4*)(dst + 4 * jj) = u;
        }
    }
}

// ---------------------------------------------------------------------------
// Kernel 1: QKV GEMM, bf16 MFMA 16x16x32, BK=64 (8 barriers instead of 16).
// Q/K o-tiles: C = W*X -> Ct [n][o] -> q/k [bh][n][64] (q pre-scaled QSCALE).
// V  o-tiles: swapped operands (C^T = X*W) -> vbuf TRANSPOSED [bh][d][n].
// LDS stride 72 ushorts: frag-read banks 4*(ln+quad) per 8-lane phase -> free.
// ---------------------------------------------------------------------------
__global__ __launch_bounds__(256)
void qkv_gemm(const ushort* __restrict__ xb, const ushort* __restrict__ wb,
              const float* __restrict__ bias,
              ushort* __restrict__ qb, ushort* __restrict__ kb, ushort* __restrict__ vb)
{
    __shared__ ushort lds[18432];        // 36.9 KB; staging + epilogue alias
    ushort* As = lds;                    // [128 o][72] (64 data + 8 pad)
    ushort* Bs = lds + 9216;             // [128 n][72]

    const int t = threadIdx.x;
    const int w = t >> 6, lane = t & 63, quad = lane >> 4, ln = lane & 15;
    const int n0 = blockIdx.x * 128;
    const int o0 = blockIdx.y * 128;
    const int b  = blockIdx.z;
    const int ow = (w & 1) * 64, nw = (w >> 1) * 64;
    const bool vpath = (o0 >= 1024);

    f4 acc[4][4];
#pragma unroll
    for (int i = 0; i < 4; ++i)
#pragma unroll
        for (int j = 0; j < 4; ++j) acc[i][j] = (f4){0.f, 0.f, 0.f, 0.f};

    const int rr = t >> 2, cc = (t & 3) * 16;
    for (int k0 = 0; k0 < Cin; k0 += 64) {
        __syncthreads();
#pragma unroll
        for (int p = 0; p < 2; ++p) {   // stage 128 rows x 64 k for A and B
            const int row = rr + p * 64;
            const ushort* sa = &wb[(o0 + row) * Cin + k0 + cc];
            *(uint4*)&As[row * 72 + cc]     = *(const uint4*)sa;
            *(uint4*)&As[row * 72 + cc + 8] = *(const uint4*)(sa + 8);
            const ushort* sb = &xb[((b << 10) + n0 + row) * Cin + k0 + cc];
            *(uint4*)&Bs[row * 72 + cc]     = *(const uint4*)sb;
            *(uint4*)&Bs[row * 72 + cc + 8] = *(const uint4*)(sb + 8);
        }
        __syncthreads();
#pragma unroll
        for (int sub = 0; sub < 2; ++sub) {
            short8 af[4], bf[4];
#pragma unroll
            for (int ot = 0; ot < 4; ++ot)
                af[ot] = *(const short8*)&As[(ow + ot * 16 + ln) * 72 + sub * 32 + quad * 8];
#pragma unroll
            for (int nt = 0; nt < 4; ++nt)
                bf[nt] = *(const short8*)&Bs[(nw + nt * 16 + ln) * 72 + sub * 32 + quad * 8];
            if (!vpath) {   // acc[ot][nt]: row = o, col = n
#pragma unroll
                for (int ot = 0; ot < 4; ++ot)
#pragma unroll
                    for (int nt = 0; nt < 4; ++nt)
                        acc[ot][nt] = __builtin_amdgcn_mfma_f32_16x16x32_bf16(
                            af[ot], bf[nt], acc[ot][nt], 0, 0, 0);
            } else {        // acc[nt][ot]: row = n, col = o (transposed C)
#pragma unroll
                for (int nt = 0; nt < 4; ++nt)
#pragma unroll
                    for (int ot = 0; ot < 4; ++ot)
                        acc[nt][ot] = __builtin_amdgcn_mfma_f32_16x16x32_bf16(
                            bf[nt], af[ot], acc[nt][ot], 0, 0, 0);
            }
        }
    }

    __syncthreads();                     // staging reads done; alias lds
    if (!vpath) {
        // ---- Q/K epilogue: Ct [n][136 o-stride], vectorized both ways ----
        ushort* Ct = lds;
        const float sc = (o0 < 512) ? QSCALE : 1.0f;
#pragma unroll
        for (int ot = 0; ot < 4; ++ot) {
            float bs[4];
#pragma unroll
            for (int rg = 0; rg < 4; ++rg)
                bs[rg] = bias[o0 + ow + ot * 16 + quad * 4 + rg];
#pragma unroll
            for (int nt = 0; nt < 4; ++nt) {
                ushort4 u;
                u.x = f2b((acc[ot][nt][0] + bs[0]) * sc);
                u.y = f2b((acc[ot][nt][1] + bs[1]) * sc);
                u.z = f2b((acc[ot][nt][2] + bs[2]) * sc);
                u.w = f2b((acc[ot][nt][3] + bs[3]) * sc);
                *(ushort4*)&Ct[(nw + nt * 16 + ln) * 136 + ow + ot * 16 + quad * 4] = u;
            }
        }
        __syncthreads();
        ushort* dst; int obase;
        if (o0 < 512) { dst = qb; obase = o0; }
        else          { dst = kb; obase = o0 - 512; }
        const int rn = t >> 1, hf = t & 1;
        const int bh = b * 8 + (obase >> 6) + hf;
        ushort* drow = &dst[(bh * Np + n0 + rn) << 6];
        const ushort* srow = &Ct[rn * 136 + hf * 64];
#pragma unroll
        for (int s = 0; s < 8; ++s)
            *(uint4*)(drow + s * 8) = *(const uint4*)(srow + s * 8);
    } else {
        // ---- V epilogue: Ct [o][136 n-stride] (rows = d), then [bh][d][n] ----
        ushort* Ct = lds;
#pragma unroll
        for (int ot = 0; ot < 4; ++ot) {
            const float bo = bias[o0 + ow + ot * 16 + ln];
#pragma unroll
            for (int nt = 0; nt < 4; ++nt) {
                ushort4 u;
                u.x = f2b(acc[nt][ot][0] + bo);
                u.y = f2b(acc[nt][ot][1] + bo);
                u.z = f2b(acc[nt][ot][2] + bo);
                u.w = f2b(acc[nt][ot][3] + bo);
                *(ushort4*)&Ct[(ow + ot * 16 + ln) * 136 + nw + nt * 16 + quad * 4] = u;
            }
        }
        __syncthreads();
        const int o_l = t >> 1, nh = (t & 1) * 64;
        const int bh = b * 8 + ((o0 - 1024) >> 6) + (o_l >> 6);
        ushort* drow = &vb[((size_t)bh << 16) + ((o_l & 63) << 10) + n0 + nh];
        const ushort* srow = &Ct[o_l * 136 + nh];
#pragma unroll
        for (int s = 0; s < 8; ++s)
            *(uint4*)(drow + s * 8) = *(const uint4*)(srow + s * 8);
    }
}

// ---------------------------------------------------------------------------
// Kernel 2: causal flash attention, bf16 MFMA, fp32 softmax in LOG2 domain
// (q pre-scaled by dh^-0.5 * log2e, so P = exp2(s-m) = single v_exp_f32).
// S^T = K*Q^T: softmax state is one scalar per lane; P store to A-layout
// [q][k] is 4x ushort4; V pre-transposed [bh][d][n] -> vector Vt staging.
// ---------------------------------------------------------------------------
__global__ __launch_bounds__(256, 4)
void attn(const ushort* __restrict__ qb, const ushort* __restrict__ kb,
          const ushort* __restrict__ vt, ushort* __restrict__ ob)
{
    __shared__ ushort Qs[64 * 72];   // [q][d]
    __shared__ ushort Ks[64 * 72];   // [k][d]
    __shared__ ushort Vt[64 * 72];   // [d][k]
    __shared__ ushort Ps[64 * 72];   // [q][k]

    const int t    = threadIdx.x;
    const int w    = t >> 6;
    const int lane = t & 63;
    const int quad = lane >> 4;
    const int ln   = lane & 15;
    const int bh   = blockIdx.x & 127;
    const int qt   = 15 - (blockIdx.x >> 7);   // heavy blocks first
    const int q0   = qt * 64;

    {   // stage Q tile
        const int r = t & 63, seg = t >> 6;
        const ushort* src = &qb[((bh * Np + q0 + r) << 6) + seg * 16];
        *(uint4*)&Qs[r * 72 + seg * 16]     = *(const uint4*)src;
        *(uint4*)&Qs[r * 72 + seg * 16 + 8] = *(const uint4*)(src + 8);
    }
    __syncthreads();

    const short8 qa0 = *(const short8*)&Qs[(w * 16 + ln) * 72 + quad * 8];
    const short8 qa1 = *(const short8*)&Qs[(w * 16 + ln) * 72 + 32 + quad * 8];

    f4 o_[4];
#pragma unroll
    for (int nt = 0; nt < 4; ++nt) o_[nt] = (f4){0.f, 0.f, 0.f, 0.f};
    float mrun = -INFINITY, lrun = 0.f;   // state for q = q0 + w*16 + ln

    for (int kt = 0; kt <= qt; ++kt) {
        __syncthreads();
        {   // stage K [k][d] and Vt [d][k] (both pure vector copies)
            const int r = t & 63, seg = t >> 6;
            const ushort* sk = &kb[((bh * Np + kt * 64 + r) << 6) + seg * 16];
            *(uint4*)&Ks[r * 72 + seg * 16]     = *(const uint4*)sk;
            *(uint4*)&Ks[r * 72 + seg * 16 + 8] = *(const uint4*)(sk + 8);
            const int dd = t >> 2, c = (t & 3) * 16;
            const ushort* sv = &vt[((size_t)bh << 16) + (dd << 10) + kt * 64 + c];
            *(uint4*)&Vt[dd * 72 + c]     = *(const uint4*)sv;
            *(uint4*)&Vt[dd * 72 + c + 8] = *(const uint4*)(sv + 8);
        }
        __syncthreads();

        const bool diag = (kt == qt);

        // ---- S^T = K Q^T : rows k = mt*16+quad*4+rg, col q = ln (log2 domain)
        f4 st[4];
#pragma unroll
        for (int mt = 0; mt < 4; ++mt) st[mt] = (f4){0.f, 0.f, 0.f, 0.f};
#pragma unroll
        for (int mt = 0; mt < 4; ++mt) {
            if (diag && mt > w) continue;   // fully-masked tile (wave-uniform)
            const short8 ka0 = *(const short8*)&Ks[(mt * 16 + ln) * 72 + quad * 8];
            const short8 ka1 = *(const short8*)&Ks[(mt * 16 + ln) * 72 + 32 + quad * 8];
            st[mt] = __builtin_amdgcn_mfma_f32_16x16x32_bf16(ka0, qa0, st[mt], 0, 0, 0);
            st[mt] = __builtin_amdgcn_mfma_f32_16x16x32_bf16(ka1, qa1, st[mt], 0, 0, 0);
        }

        if (diag) {   // mask k > q
            const int qrow = w * 16 + ln;
#pragma unroll
            for (int mt = 0; mt < 4; ++mt)
#pragma unroll
                for (int rg = 0; rg < 4; ++rg)
                    if (mt * 16 + quad * 4 + rg > qrow) st[mt][rg] = -INFINITY;
        }

        // ---- online softmax (log2 domain): scalar state per lane
        float mx = -INFINITY;
#pragma unroll
        for (int mt = 0; mt < 4; ++mt)
#pragma unroll
            for (int rg = 0; rg < 4; ++rg) mx = fmaxf(mx, st[mt][rg]);
        mx = fmaxf(mx, __shfl_xor(mx, 16));
        mx = fmaxf(mx, __shfl_xor(mx, 32));

        const float mn = fmaxf(mrun, mx);
        const float al = EXP2(mrun - mn);   // first tile: exp2(-inf)=0
        mrun = mn;

        float rs = 0.f;
        const int prow = (w * 16 + ln) * 72;
#pragma unroll
        for (int mt = 0; mt < 4; ++mt) {
            float p0 = EXP2(st[mt][0] - mn), p1 = EXP2(st[mt][1] - mn);
            float p2 = EXP2(st[mt][2] - mn), p3 = EXP2(st[mt][3] - mn);
            rs += (p0 + p1) + (p2 + p3);
            ushort4 u; u.x = f2b(p0); u.y = f2b(p1); u.z = f2b(p2); u.w = f2b(p3);
            *(ushort4*)&Ps[prow + mt * 16 + quad * 4] = u;
        }
        rs += __shfl_xor(rs, 16);
        rs += __shfl_xor(rs, 32);
        lrun = lrun * al + rs;

        float alr[4];   // alpha for O rows quad*4+rg
#pragma unroll
        for (int rg = 0; rg < 4; ++rg) alr[rg] = __shfl(al, quad * 4 + rg);
#pragma unroll
        for (int nt = 0; nt < 4; ++nt)
#pragma unroll
            for (int rg = 0; rg < 4; ++rg) o_[nt][rg] *= alr[rg];

        // ---- O += P V (wave-private P rows)
#pragma unroll
        for (int ks = 0; ks < 2; ++ks) {
            if (diag && w * 16 + 15 < ks * 32) continue;   // zero P half
            const short8 pa = *(const short8*)&Ps[prow + ks * 32 + quad * 8];
#pragma unroll
            for (int nt = 0; nt < 4; ++nt) {
                const short8 vf = *(const short8*)&Vt[(nt * 16 + ln) * 72 + ks * 32 + quad * 8];
                o_[nt] = __builtin_amdgcn_mfma_f32_16x16x32_bf16(pa, vf, o_[nt], 0, 0, 0);
            }
        }
    }

    // ---- epilogue: O / l -> bf16 ob [bh][q][64]
    const float linv = 1.0f / lrun;
    float lr[4];
#pragma unroll
    for (int rg = 0; rg < 4; ++rg) lr[rg] = __shfl(linv, quad * 4 + rg);
#pragma unroll
    for (int rg = 0; rg < 4; ++rg) {
        const int rr = q0 + w * 16 + quad * 4 + rg;
#pragma unroll
        for (int nt = 0; nt < 4; ++nt)
            ob[((bh * Np + rr) << 6) + nt * 16 + ln] = f2b(o_[nt][rg] * lr[rg]);
    }
}

// ---------------------------------------------------------------------------
// Kernel 3: projection GEMM, bf16 MFMA, 64(o) x 128(n) tile, BK=64.
// Grid 512 blocks (2/CU). Wave w owns n strip [w*32, w*32+32).
// ---------------------------------------------------------------------------
__global__ __launch_bounds__(256)
void proj_gemm(const ushort* __restrict__ obuf, const ushort* __restrict__ pwb,
               const float* __restrict__ bias, float* __restrict__ out)
{
    __shared__ ushort As[64 * 72];    // pw [o][k]
    __shared__ ushort Bs[128 * 72];   // attn-out [n][k]

    const int t = threadIdx.x;
    const int w = t >> 6, lane = t & 63, quad = lane >> 4, ln = lane & 15;
    const int n0 = blockIdx.x * 128;
    const int o0 = blockIdx.y * 64;
    const int b  = blockIdx.z;
    const int nw = w * 32;

    f4 acc[4][2];
#pragma unroll
    for (int i = 0; i < 4; ++i)
#pragma unroll
        for (int j = 0; j < 2; ++j) acc[i][j] = (f4){0.f, 0.f, 0.f, 0.f};

    const int rr = t >> 2, cc = (t & 3) * 16;
    for (int k0 = 0; k0 < 512; k0 += 64) {
        __syncthreads();
        {   // A: 64 o-rows x 64 k; B: 128 n-rows x 64 k (one head per step)
            const ushort* sa = &pwb[(o0 + rr) * 512 + k0 + cc];
            *(uint4*)&As[rr * 72 + cc]     = *(const uint4*)sa;
            *(uint4*)&As[rr * 72 + cc + 8] = *(const uint4*)(sa + 8);
            const int head = k0 >> 6;
#pragma unroll
            for (int p = 0; p < 2; ++p) {
                const int row = rr + p * 64;
                const ushort* sb = &obuf[(((b * 8 + head) * Np + n0 + row) << 6) + cc];
                *(uint4*)&Bs[row * 72 + cc]     = *(const uint4*)sb;
                *(uint4*)&Bs[row * 72 + cc + 8] = *(const uint4*)(sb + 8);
            }
        }
        __syncthreads();
#pragma unroll
        for (int sub = 0; sub < 2; ++sub) {
            short8 af[4], bf[2];
#pragma unroll
            for (int ot = 0; ot < 4; ++ot)
                af[ot] = *(const short8*)&As[(ot * 16 + ln) * 72 + sub * 32 + quad * 8];
#pragma unroll
            for (int nt = 0; nt < 2; ++nt)
                bf[nt] = *(const short8*)&Bs[(nw + nt * 16 + ln) * 72 + sub * 32 + quad * 8];
#pragma unroll
            for (int ot = 0; ot < 4; ++ot)
#pragma unroll
                for (int nt = 0; nt < 2; ++nt)
                    acc[ot][nt] = __builtin_amdgcn_mfma_f32_16x16x32_bf16(
                        af[ot], bf[nt], acc[ot][nt], 0, 0, 0);
        }
    }

    // epilogue: direct fp32 stores (16-lane 64B segments), bias added
#pragma unroll
    for (int ot = 0; ot < 4; ++ot) {
#pragma unroll
        for (int rg = 0; rg < 4; ++rg) {
            const int oo = o0 + ot * 16 + quad * 4 + rg;
            const float pb = bias[oo];
            float* drow = &out[((b << 8) + oo) << 10];
#pragma unroll
            for (int nt = 0; nt < 2; ++nt)
                drow[n0 + nw + nt * 16 + ln] = acc[ot][nt][rg] + pb;
        }
    }
}

// ---------------------------------------------------------------------------
extern "C" void kernel_launch(void* const* d_in, const int* in_sizes, int n_in,
                              void* d_out, int out_size, void* d_ws, size_t ws_size,
                              hipStream_t stream)
{
    const float* x   = (const float*)d_in[0];   // [16,256,1024]
    const float* qw  = (const float*)d_in[1];   // [1536,256]
    const float* qbb = (const float*)d_in[2];   // [1536]
    const float* pw  = (const float*)d_in[3];   // [256,512]
    const float* pb  = (const float*)d_in[4];   // [256]
    float* out = (float*)d_out;                 // [16,256,1024]

    // workspace (all bf16): q/k [bh][n][64], v TRANSPOSED [bh][64][n],
    // attn-out [bh][n][64]; xb [b][n][c]; weights.
    const size_t per = (size_t)Bsz * 8 * Np * 64;
    ushort* qbuf = (ushort*)d_ws;
    ushort* kbuf = qbuf + per;
    ushort* vbuf = kbuf + per;
    ushort* obuf = vbuf + per;
    ushort* xb   = obuf + per;
    ushort* qwb  = xb + (size_t)Bsz * Np * Cin;
    ushort* pwb  = qwb + 1536 * Cin;

    cast_xw<<<dim3(16, 5, Bsz), 256, 0, stream>>>(x, qw, pw, xb, qwb, pwb);
    qkv_gemm<<<dim3(8, 12, Bsz), 256, 0, stream>>>(xb, qwb, qbb, qbuf, kbuf, vbuf);
    attn<<<dim3(128 * 16), 256, 0, stream>>>(qbuf, kbuf, vbuf, obuf);
    proj_gemm<<<dim3(8, 4, Bsz), 256, 0, stream>>>(obuf, pwb, pb, out);
}